// Round 8
// baseline (932.836 us; speedup 1.0000x reference)
//
#include <hip/hip_runtime.h>
#include <math.h>

// Problem constants
#define B_   8
#define P_   1024
#define D_   768
#define NEGV -1000000000.0f

// ---------------------------------------------------------------------------
// Kernel A: fp32 GEMM replicating OpenBLAS sgemm accumulation (UNCHANGED MATH:
// per-output 768 sequential-d FMAs, kc=384 panel break, (p1+p2)+bias).
// 128x128 tile, 8x8 microtile, kc=16, 256 threads, two-pass global spill.
// NEW vs r7: double-buffered LDS, one barrier per iteration — next-tile
// global loads stay in flight during compute (removes the vmcnt(0)+barrier
// drain that left 38% of cycles idle).
// ---------------------------------------------------------------------------
__global__ __launch_bounds__(256) void gemm_qkv_np(
    const float* __restrict__ x,
    const float* __restrict__ Wq, const float* __restrict__ bq,
    const float* __restrict__ Wk, const float* __restrict__ bk,
    const float* __restrict__ Wv, const float* __restrict__ bv,
    float* __restrict__ Qo, float* __restrict__ Ko, float* __restrict__ Vo)
{
    const int which = blockIdx.z;
    const float* __restrict__ W    = (which == 0) ? Wq : (which == 1) ? Wk : Wv;
    const float* __restrict__ bias = (which == 0) ? bq : (which == 1) ? bk : bv;
    float* __restrict__ Out        = (which == 0) ? Qo : (which == 1) ? Ko : Vo;

    const int n0 = blockIdx.x * 128;
    const int m0 = blockIdx.y * 128;
    const int t  = threadIdx.x;
    const int tx = t & 15, ty = t >> 4;

    __shared__ float As[2][16 * 132];   // [buf][d][row], stride 132
    __shared__ float Bs[2][16 * 132];   // [buf][d][col]

    // A staging: each thread loads 2 rows (ra, ra+64), one 4-wide d-group
    const int  ra  = t >> 2, ca = t & 3;
    const int  ar0 = m0 + ra;
    const int  ar1 = m0 + ra + 64;
    const long a_off0 = ((long)(ar0 >> 10) * 1025 + 1 + (ar0 & 1023)) * D_; // skip token 0
    const long a_off1 = ((long)(ar1 >> 10) * 1025 + 1 + (ar1 & 1023)) * D_;
    // B staging: each thread loads 2 d-rows (db, db+8), one 4-wide col-group
    const int  db = t >> 5, cb = t & 31;

    const float* xa0 = x + a_off0 + 4 * ca;
    const float* xa1 = x + a_off1 + 4 * ca;
    const float* wb0 = W + (long)db * D_ + n0 + 4 * cb;
    const float* wb1 = W + (long)(db + 8) * D_ + n0 + 4 * cb;

    float acc[8][8] = {};

    auto stage = [&](int bsel, const float4& av0, const float4& av1,
                     const float4& bw0, const float4& bw1) {
        float* A  = As[bsel];
        float* Bx = Bs[bsel];
        A[(4 * ca + 0) * 132 + ra]      = av0.x;
        A[(4 * ca + 1) * 132 + ra]      = av0.y;
        A[(4 * ca + 2) * 132 + ra]      = av0.z;
        A[(4 * ca + 3) * 132 + ra]      = av0.w;
        A[(4 * ca + 0) * 132 + ra + 64] = av1.x;
        A[(4 * ca + 1) * 132 + ra + 64] = av1.y;
        A[(4 * ca + 2) * 132 + ra + 64] = av1.z;
        A[(4 * ca + 3) * 132 + ra + 64] = av1.w;
        *reinterpret_cast<float4*>(&Bx[db * 132 + 4 * cb])       = bw0;
        *reinterpret_cast<float4*>(&Bx[(db + 8) * 132 + 4 * cb]) = bw1;
    };

    auto run_pass = [&](int dstart) {
        float4 av0 = *reinterpret_cast<const float4*>(xa0 + dstart);
        float4 av1 = *reinterpret_cast<const float4*>(xa1 + dstart);
        float4 bw0 = *reinterpret_cast<const float4*>(wb0 + (long)dstart * D_);
        float4 bw1 = *reinterpret_cast<const float4*>(wb1 + (long)dstart * D_);
        __syncthreads();                 // protect buf0 from prior-pass readers
        stage(0, av0, av1, bw0, bw1);
        __syncthreads();                 // buf0 ready

        for (int it = 0; it < 24; ++it) {
            const int cur = it & 1;
            if (it < 23) {               // issue next-tile loads (stay in flight)
                const int dn = dstart + 16 * (it + 1);
                av0 = *reinterpret_cast<const float4*>(xa0 + dn);
                av1 = *reinterpret_cast<const float4*>(xa1 + dn);
                bw0 = *reinterpret_cast<const float4*>(wb0 + (long)dn * D_);
                bw1 = *reinterpret_cast<const float4*>(wb1 + (long)dn * D_);
            }
            const float* Ab = As[cur];
            const float* Bb = Bs[cur];
#pragma unroll
            for (int d = 0; d < 16; ++d) {
                float4 a0 = *reinterpret_cast<const float4*>(&Ab[d * 132 + 8 * ty]);
                float4 a1 = *reinterpret_cast<const float4*>(&Ab[d * 132 + 8 * ty + 4]);
                float4 b0 = *reinterpret_cast<const float4*>(&Bb[d * 132 + 8 * tx]);
                float4 b1 = *reinterpret_cast<const float4*>(&Bb[d * 132 + 8 * tx + 4]);
                float a[8] = {a0.x, a0.y, a0.z, a0.w, a1.x, a1.y, a1.z, a1.w};
                float b[8] = {b0.x, b0.y, b0.z, b0.w, b1.x, b1.y, b1.z, b1.w};
#pragma unroll
                for (int i = 0; i < 8; ++i)
#pragma unroll
                    for (int j = 0; j < 8; ++j)
                        acc[i][j] = fmaf(a[i], b[j], acc[i][j]);
            }
            if (it < 23) {
                stage(1 - cur, av0, av1, bw0, bw1);
                __syncthreads();         // nbuf ready; protects cur rewrite next iter
            }
        }
    };

    // ---- pass 1: d = 0..383 ----
    run_pass(0);

    // spill panel-1 raw sums to Out (overwritten by the epilogue below)
#pragma unroll
    for (int i = 0; i < 8; ++i) {
        const long r = m0 + 8 * ty + i;
        float* orow = Out + r * D_ + n0 + 8 * tx;
        float4 o0 = {acc[i][0], acc[i][1], acc[i][2], acc[i][3]};
        float4 o1 = {acc[i][4], acc[i][5], acc[i][6], acc[i][7]};
        *reinterpret_cast<float4*>(orow)     = o0;
        *reinterpret_cast<float4*>(orow + 4) = o1;
#pragma unroll
        for (int j = 0; j < 8; ++j) acc[i][j] = 0.0f;
    }

    // ---- pass 2: d = 384..767 ----
    run_pass(384);

    // epilogue: reload panel-1, exact round-3 bracket (p1 + p2) + bias
    float bcol[8];
#pragma unroll
    for (int u = 0; u < 2; ++u) {
        float4 bb = *reinterpret_cast<const float4*>(bias + n0 + 8 * tx + 4 * u);
        bcol[4 * u + 0] = bb.x; bcol[4 * u + 1] = bb.y;
        bcol[4 * u + 2] = bb.z; bcol[4 * u + 3] = bb.w;
    }
#pragma unroll
    for (int i = 0; i < 8; ++i) {
        const long r = m0 + 8 * ty + i;
        float* orow = Out + r * D_ + n0 + 8 * tx;
        float4 p10 = *reinterpret_cast<float4*>(orow);
        float4 p11 = *reinterpret_cast<float4*>(orow + 4);
        float p1[8] = {p10.x, p10.y, p10.z, p10.w, p11.x, p11.y, p11.z, p11.w};
#pragma unroll
        for (int u = 0; u < 2; ++u) {
            float4 o;
            float s0 = __fadd_rn(p1[4 * u + 0], acc[i][4 * u + 0]);
            float s1 = __fadd_rn(p1[4 * u + 1], acc[i][4 * u + 1]);
            float s2 = __fadd_rn(p1[4 * u + 2], acc[i][4 * u + 2]);
            float s3 = __fadd_rn(p1[4 * u + 3], acc[i][4 * u + 3]);
            o.x = __fadd_rn(s0, bcol[4 * u + 0]);
            o.y = __fadd_rn(s1, bcol[4 * u + 1]);
            o.z = __fadd_rn(s2, bcol[4 * u + 2]);
            o.w = __fadd_rn(s3, bcol[4 * u + 3]);
            *reinterpret_cast<float4*>(orow + 4 * u) = o;
        }
    }
}

// ---------------------------------------------------------------------------
// Kernel B: row L2-normalize replicating numpy pairwise tree (VERBATIM).
// ---------------------------------------------------------------------------
__global__ __launch_bounds__(256) void l2norm_np(float* __restrict__ Q,
                                                 float* __restrict__ K)
{
    const int gid  = blockIdx.x * 256 + threadIdx.x;
    const int w    = gid >> 6;
    const int lane = gid & 63;
    const int wl   = threadIdx.x >> 6;
    float* __restrict__ base = (w < 8192) ? Q : K;
    const long row = (long)(w & 8191);
    float* p = base + row * D_;

    const int bb = lane >> 3, jj = lane & 7;
    const float* seg = p + 96 * bb + jj;
    float r = 0.0f;
#pragma unroll
    for (int i = 0; i < 12; ++i) {
        float xv = seg[8 * i];
        r = __fadd_rn(r, __fmul_rn(xv, xv));
    }

    __shared__ float red[4][64];
    red[wl][lane] = r;
    __syncthreads();

    float Bv[8];
#pragma unroll
    for (int b2 = 0; b2 < 8; ++b2) {
        const float* rr = &red[wl][8 * b2];
        float t1 = __fadd_rn(rr[0], rr[1]);
        float t2 = __fadd_rn(rr[2], rr[3]);
        float t3 = __fadd_rn(rr[4], rr[5]);
        float t4 = __fadd_rn(rr[6], rr[7]);
        Bv[b2] = __fadd_rn(__fadd_rn(t1, t2), __fadd_rn(t3, t4));
    }
    float s01 = __fadd_rn(Bv[0], Bv[1]), s23 = __fadd_rn(Bv[2], Bv[3]);
    float s45 = __fadd_rn(Bv[4], Bv[5]), s67 = __fadd_rn(Bv[6], Bv[7]);
    float tot = __fadd_rn(__fadd_rn(s01, s23), __fadd_rn(s45, s67));

    const float nm = fmaxf(__fsqrt_rn(tot), 1e-12f);

    float* q = p + lane * 12;
#pragma unroll
    for (int i = 0; i < 12; ++i) q[i] = __fdiv_rn(q[i], nm);
}

// ---------------------------------------------------------------------------
// Kernel C: scores, quad-split numpy 16-chain tree (VERBATIM, known-pass).
// ---------------------------------------------------------------------------
__global__ __launch_bounds__(256) void scores_np(
    const float* __restrict__ Q, const float* __restrict__ K,
    const float* __restrict__ pb, float* __restrict__ S)
{
    const int bz = blockIdx.z;
    const int n0 = blockIdx.x * 32;   // cols
    const int m0 = blockIdx.y * 32;   // rows
    const int t  = threadIdx.x;
    const int q    = t & 3;           // chain-slot lane within quad
    const int quad = t >> 2;          // 0..63
    const int qx   = quad & 7;        // col group (4 cols)
    const int qy   = quad >> 3;       // row group (4 rows)

    __shared__ float Qs[16 * 36];     // [dd][row], stride 36
    __shared__ float Ks[16 * 36];     // [dd][col], stride 36

    const float* Qb = Q + (((long)bz << 10) + m0) * D_;
    const float* Kb = K + (((long)bz << 10) + n0) * D_;

    const int sr = (t & 127) >> 2;    // row 0..31
    const int sg = t & 3;             // d-group 0..3
    const float* gsrc = (t < 128) ? (Qb + (long)sr * D_ + 4 * sg)
                                  : (Kb + (long)sr * D_ + 4 * sg);
    float* lw = (t < 128) ? Qs : Ks;

    float acc[4][4][4] = {};          // [s][i][j]

    for (int d0 = 0; d0 < D_; d0 += 16) {
        __syncthreads();
        float4 g = *reinterpret_cast<const float4*>(gsrc + d0);
        lw[(4 * sg + 0) * 36 + sr] = g.x;
        lw[(4 * sg + 1) * 36 + sr] = g.y;
        lw[(4 * sg + 2) * 36 + sr] = g.z;
        lw[(4 * sg + 3) * 36 + sr] = g.w;
        __syncthreads();

#pragma unroll
        for (int s = 0; s < 4; ++s) {
            const int dd = q + 4 * s;
            float4 qv = *reinterpret_cast<const float4*>(&Qs[dd * 36 + 4 * qy]);
            float4 kv = *reinterpret_cast<const float4*>(&Ks[dd * 36 + 4 * qx]);
            float a[4] = {qv.x, qv.y, qv.z, qv.w};
            float b[4] = {kv.x, kv.y, kv.z, kv.w};
#pragma unroll
            for (int i = 0; i < 4; ++i)
#pragma unroll
                for (int j = 0; j < 4; ++j)
                    acc[s][i][j] = fmaf(a[i], b[j], acc[s][i][j]);
        }
    }

    float dot[4][4];
#pragma unroll
    for (int i = 0; i < 4; ++i)
#pragma unroll
        for (int j = 0; j < 4; ++j) {
            float ylo = __fadd_rn(acc[0][i][j], acc[2][i][j]);
            float yhi = __fadd_rn(acc[1][i][j], acc[3][i][j]);
            float zz  = __fadd_rn(ylo, yhi);
            float zr  = __shfl_xor(zz, 2, 64);
            float t2  = __fadd_rn(zz, zr);          // lane0: z0+z2, lane1: z1+z3
            float tr  = __shfl_xor(t2, 1, 64);
            dot[i][j] = __fadd_rn(t2, tr);          // lane0: (z0+z2)+(z1+z3)
        }

    if (q == 0) {
        const int c0 = n0 + 4 * qx;
#pragma unroll
        for (int i = 0; i < 4; ++i) {
            const int p = m0 + 4 * qy + i;
            float4 pbv = *reinterpret_cast<const float4*>(pb + (long)p * P_ + c0);
            float v[4] = {__fadd_rn(dot[i][0], pbv.x), __fadd_rn(dot[i][1], pbv.y),
                          __fadd_rn(dot[i][2], pbv.z), __fadd_rn(dot[i][3], pbv.w)};
#pragma unroll
            for (int j = 0; j < 4; ++j)
                if (c0 + j == p) v[j] = NEGV;
            float4 o = {v[0], v[1], v[2], v[3]};
            *reinterpret_cast<float4*>(S + (((long)bz << 10) + p) * P_ + c0) = o;
        }
    }
}

// ---------------------------------------------------------------------------
// Kernel D: top-16 + softmax + V gather (VERBATIM).
// ---------------------------------------------------------------------------
__global__ __launch_bounds__(256) void topk_np(
    const float* __restrict__ S, const float* __restrict__ V,
    float* __restrict__ out)
{
    const int gid  = blockIdx.x * 256 + threadIdx.x;
    const int gw   = gid >> 6;          // row id 0..8191
    const int lane = gid & 63;
    const int b    = gw >> 10;

    const float* srow = S + ((long)gw << 10);
    float s[16];
#pragma unroll
    for (int t = 0; t < 16; ++t) s[t] = __fdiv_rn(srow[lane + 64 * t], 0.1f);

    float topv[16];
    int   topi[16];
#pragma unroll
    for (int r = 0; r < 16; ++r) {
        float bvv = s[0];
        int   bt  = 0;
#pragma unroll
        for (int t = 1; t < 16; ++t)
            if (s[t] > bvv) { bvv = s[t]; bt = t; }
        int bi = lane + 64 * bt;
#pragma unroll
        for (int m = 1; m < 64; m <<= 1) {
            float ov = __shfl_xor(bvv, m, 64);
            int   oi = __shfl_xor(bi, m, 64);
            if (ov > bvv || (ov == bvv && oi < bi)) { bvv = ov; bi = oi; }
        }
        topv[r] = bvv;
        topi[r] = bi;
#pragma unroll
        for (int t = 0; t < 16; ++t)
            if (lane + 64 * t == bi) s[t] = -3.0e38f;
    }

    const float mx = topv[0];
    float e[16];
#pragma unroll
    for (int r = 0; r < 16; ++r) e[r] = expf(topv[r] - mx);
    float r8[8];
#pragma unroll
    for (int j = 0; j < 8; ++j) r8[j] = __fadd_rn(e[j], e[j + 8]);
    float t1 = __fadd_rn(r8[0], r8[1]);
    float t2 = __fadd_rn(r8[2], r8[3]);
    float t3 = __fadd_rn(r8[4], r8[5]);
    float t4 = __fadd_rn(r8[6], r8[7]);
    float sum = __fadd_rn(__fadd_rn(t1, t2), __fadd_rn(t3, t4));
    float wgt[16];
#pragma unroll
    for (int r = 0; r < 16; ++r) wgt[r] = __fdiv_rn(e[r], sum);

    float4 a0 = {0, 0, 0, 0}, a1 = {0, 0, 0, 0}, a2 = {0, 0, 0, 0};
    const float* vb = V + ((long)b << 10) * D_;
#pragma unroll
    for (int r = 0; r < 16; ++r) {
        const float* vr = vb + (long)topi[r] * D_ + lane * 12;
        const float wr = wgt[r];
        float4 x0 = *reinterpret_cast<const float4*>(vr);
        float4 x1 = *reinterpret_cast<const float4*>(vr + 4);
        float4 x2 = *reinterpret_cast<const float4*>(vr + 8);
        a0.x = fmaf(wr, x0.x, a0.x); a0.y = fmaf(wr, x0.y, a0.y);
        a0.z = fmaf(wr, x0.z, a0.z); a0.w = fmaf(wr, x0.w, a0.w);
        a1.x = fmaf(wr, x1.x, a1.x); a1.y = fmaf(wr, x1.y, a1.y);
        a1.z = fmaf(wr, x1.z, a1.z); a1.w = fmaf(wr, x1.w, a1.w);
        a2.x = fmaf(wr, x2.x, a2.x); a2.y = fmaf(wr, x2.y, a2.y);
        a2.z = fmaf(wr, x2.z, a2.z); a2.w = fmaf(wr, x2.w, a2.w);
    }
    float* orow = out + (long)gw * D_ + lane * 12;
    *reinterpret_cast<float4*>(orow)     = a0;
    *reinterpret_cast<float4*>(orow + 4) = a1;
    *reinterpret_cast<float4*>(orow + 8) = a2;
}

// ---------------------------------------------------------------------------
extern "C" void kernel_launch(void* const* d_in, const int* in_sizes, int n_in,
                              void* d_out, int out_size, void* d_ws, size_t ws_size,
                              hipStream_t stream)
{
    const float* x  = (const float*)d_in[0];
    const float* Wq = (const float*)d_in[1];
    const float* bq = (const float*)d_in[2];
    const float* Wk = (const float*)d_in[3];
    const float* bk = (const float*)d_in[4];
    const float* Wv = (const float*)d_in[5];
    const float* bv = (const float*)d_in[6];
    const float* pb = (const float*)d_in[7];
    float* out = (float*)d_out;

    // Workspace (fp32): Q | K | V (8192x768 each) | S (8192x1024)
    float* ws = (float*)d_ws;
    float* Q = ws;
    float* K = Q + (size_t)B_ * P_ * D_;
    float* V = K + (size_t)B_ * P_ * D_;
    float* S = V + (size_t)B_ * P_ * D_;

    hipLaunchKernelGGL(gemm_qkv_np, dim3(6, 64, 3), dim3(256), 0, stream,
                       x, Wq, bq, Wk, bk, Wv, bv, Q, K, V);
    hipLaunchKernelGGL(l2norm_np, dim3(4096), dim3(256), 0, stream, Q, K);
    hipLaunchKernelGGL(scores_np, dim3(32, 32, 8), dim3(256), 0, stream,
                       Q, K, pb, S);
    hipLaunchKernelGGL(topk_np, dim3(2048), dim3(256), 0, stream,
                       S, V, out);
}

// Round 9
// 745.751 us; speedup vs baseline: 1.2509x; 1.2509x over previous
//
#include <hip/hip_runtime.h>
#include <math.h>

// Problem constants
#define B_   8
#define P_   1024
#define D_   768
#define NEGV -1000000000.0f

// ---------------------------------------------------------------------------
// Kernel A: fp32 GEMM replicating OpenBLAS sgemm accumulation (ROUND-7
// VERBATIM — measured 384 us, VGPR 80. Two-pass global spill, single-buffer
// LDS. NOTE: dbuf/prefetch variants measured WORSE (r4 wrong, r6 530us,
// r8 630us @ VGPR 188) — do not re-add pipelining here.)
// ---------------------------------------------------------------------------
__global__ __launch_bounds__(256) void gemm_qkv_np(
    const float* __restrict__ x,
    const float* __restrict__ Wq, const float* __restrict__ bq,
    const float* __restrict__ Wk, const float* __restrict__ bk,
    const float* __restrict__ Wv, const float* __restrict__ bv,
    float* __restrict__ Qo, float* __restrict__ Ko, float* __restrict__ Vo)
{
    const int which = blockIdx.z;
    const float* __restrict__ W    = (which == 0) ? Wq : (which == 1) ? Wk : Wv;
    const float* __restrict__ bias = (which == 0) ? bq : (which == 1) ? bk : bv;
    float* __restrict__ Out        = (which == 0) ? Qo : (which == 1) ? Ko : Vo;

    const int n0 = blockIdx.x * 128;
    const int m0 = blockIdx.y * 128;
    const int t  = threadIdx.x;
    const int tx = t & 15, ty = t >> 4;

    __shared__ float As[16 * 132];   // As[d][row], stride 132
    __shared__ float Bs[16 * 132];   // Bs[d][col]

    const int  ra  = t >> 2, ca = t & 3;
    const int  ar0 = m0 + ra;
    const int  ar1 = m0 + ra + 64;
    const long a_off0 = ((long)(ar0 >> 10) * 1025 + 1 + (ar0 & 1023)) * D_; // skip token 0
    const long a_off1 = ((long)(ar1 >> 10) * 1025 + 1 + (ar1 & 1023)) * D_;
    const int  db = t >> 5, cb = t & 31;

    float acc[8][8] = {};

    // ---- pass 1: d = 0..383 (first kc=384 panel) ----
    for (int d0 = 0; d0 < 384; d0 += 16) {
        float4 av0 = *reinterpret_cast<const float4*>(x + a_off0 + d0 + 4 * ca);
        float4 av1 = *reinterpret_cast<const float4*>(x + a_off1 + d0 + 4 * ca);
        float4 bw0 = *reinterpret_cast<const float4*>(W + (long)(d0 + db) * D_ + n0 + 4 * cb);
        float4 bw1 = *reinterpret_cast<const float4*>(W + (long)(d0 + db + 8) * D_ + n0 + 4 * cb);
        __syncthreads();
        As[(4 * ca + 0) * 132 + ra]      = av0.x;
        As[(4 * ca + 1) * 132 + ra]      = av0.y;
        As[(4 * ca + 2) * 132 + ra]      = av0.z;
        As[(4 * ca + 3) * 132 + ra]      = av0.w;
        As[(4 * ca + 0) * 132 + ra + 64] = av1.x;
        As[(4 * ca + 1) * 132 + ra + 64] = av1.y;
        As[(4 * ca + 2) * 132 + ra + 64] = av1.z;
        As[(4 * ca + 3) * 132 + ra + 64] = av1.w;
        *reinterpret_cast<float4*>(&Bs[db * 132 + 4 * cb])       = bw0;
        *reinterpret_cast<float4*>(&Bs[(db + 8) * 132 + 4 * cb]) = bw1;
        __syncthreads();
#pragma unroll
        for (int d = 0; d < 16; ++d) {
            float4 a0 = *reinterpret_cast<const float4*>(&As[d * 132 + 8 * ty]);
            float4 a1 = *reinterpret_cast<const float4*>(&As[d * 132 + 8 * ty + 4]);
            float4 b0 = *reinterpret_cast<const float4*>(&Bs[d * 132 + 8 * tx]);
            float4 b1 = *reinterpret_cast<const float4*>(&Bs[d * 132 + 8 * tx + 4]);
            float a[8] = {a0.x, a0.y, a0.z, a0.w, a1.x, a1.y, a1.z, a1.w};
            float b[8] = {b0.x, b0.y, b0.z, b0.w, b1.x, b1.y, b1.z, b1.w};
#pragma unroll
            for (int i = 0; i < 8; ++i)
#pragma unroll
                for (int j = 0; j < 8; ++j)
                    acc[i][j] = fmaf(a[i], b[j], acc[i][j]);
        }
    }

    // spill panel-1 raw sums to Out (overwritten by the epilogue below)
#pragma unroll
    for (int i = 0; i < 8; ++i) {
        const long r = m0 + 8 * ty + i;
        float* orow = Out + r * D_ + n0 + 8 * tx;
        float4 o0 = {acc[i][0], acc[i][1], acc[i][2], acc[i][3]};
        float4 o1 = {acc[i][4], acc[i][5], acc[i][6], acc[i][7]};
        *reinterpret_cast<float4*>(orow)     = o0;
        *reinterpret_cast<float4*>(orow + 4) = o1;
#pragma unroll
        for (int j = 0; j < 8; ++j) acc[i][j] = 0.0f;
    }

    // ---- pass 2: d = 384..767 (second kc=384 panel) ----
    for (int d0 = 384; d0 < 768; d0 += 16) {
        float4 av0 = *reinterpret_cast<const float4*>(x + a_off0 + d0 + 4 * ca);
        float4 av1 = *reinterpret_cast<const float4*>(x + a_off1 + d0 + 4 * ca);
        float4 bw0 = *reinterpret_cast<const float4*>(W + (long)(d0 + db) * D_ + n0 + 4 * cb);
        float4 bw1 = *reinterpret_cast<const float4*>(W + (long)(d0 + db + 8) * D_ + n0 + 4 * cb);
        __syncthreads();
        As[(4 * ca + 0) * 132 + ra]      = av0.x;
        As[(4 * ca + 1) * 132 + ra]      = av0.y;
        As[(4 * ca + 2) * 132 + ra]      = av0.z;
        As[(4 * ca + 3) * 132 + ra]      = av0.w;
        As[(4 * ca + 0) * 132 + ra + 64] = av1.x;
        As[(4 * ca + 1) * 132 + ra + 64] = av1.y;
        As[(4 * ca + 2) * 132 + ra + 64] = av1.z;
        As[(4 * ca + 3) * 132 + ra + 64] = av1.w;
        *reinterpret_cast<float4*>(&Bs[db * 132 + 4 * cb])       = bw0;
        *reinterpret_cast<float4*>(&Bs[(db + 8) * 132 + 4 * cb]) = bw1;
        __syncthreads();
#pragma unroll
        for (int d = 0; d < 16; ++d) {
            float4 a0 = *reinterpret_cast<const float4*>(&As[d * 132 + 8 * ty]);
            float4 a1 = *reinterpret_cast<const float4*>(&As[d * 132 + 8 * ty + 4]);
            float4 b0 = *reinterpret_cast<const float4*>(&Bs[d * 132 + 8 * tx]);
            float4 b1 = *reinterpret_cast<const float4*>(&Bs[d * 132 + 8 * tx + 4]);
            float a[8] = {a0.x, a0.y, a0.z, a0.w, a1.x, a1.y, a1.z, a1.w};
            float b[8] = {b0.x, b0.y, b0.z, b0.w, b1.x, b1.y, b1.z, b1.w};
#pragma unroll
            for (int i = 0; i < 8; ++i)
#pragma unroll
                for (int j = 0; j < 8; ++j)
                    acc[i][j] = fmaf(a[i], b[j], acc[i][j]);
        }
    }

    // epilogue: reload panel-1, exact round-3 bracket (p1 + p2) + bias
    float bcol[8];
#pragma unroll
    for (int u = 0; u < 2; ++u) {
        float4 bb = *reinterpret_cast<const float4*>(bias + n0 + 8 * tx + 4 * u);
        bcol[4 * u + 0] = bb.x; bcol[4 * u + 1] = bb.y;
        bcol[4 * u + 2] = bb.z; bcol[4 * u + 3] = bb.w;
    }
#pragma unroll
    for (int i = 0; i < 8; ++i) {
        const long r = m0 + 8 * ty + i;
        float* orow = Out + r * D_ + n0 + 8 * tx;
        float4 p10 = *reinterpret_cast<float4*>(orow);
        float4 p11 = *reinterpret_cast<float4*>(orow + 4);
        float p1[8] = {p10.x, p10.y, p10.z, p10.w, p11.x, p11.y, p11.z, p11.w};
#pragma unroll
        for (int u = 0; u < 2; ++u) {
            float4 o;
            float s0 = __fadd_rn(p1[4 * u + 0], acc[i][4 * u + 0]);
            float s1 = __fadd_rn(p1[4 * u + 1], acc[i][4 * u + 1]);
            float s2 = __fadd_rn(p1[4 * u + 2], acc[i][4 * u + 2]);
            float s3 = __fadd_rn(p1[4 * u + 3], acc[i][4 * u + 3]);
            o.x = __fadd_rn(s0, bcol[4 * u + 0]);
            o.y = __fadd_rn(s1, bcol[4 * u + 1]);
            o.z = __fadd_rn(s2, bcol[4 * u + 2]);
            o.w = __fadd_rn(s3, bcol[4 * u + 3]);
            *reinterpret_cast<float4*>(orow + 4 * u) = o;
        }
    }
}

// ---------------------------------------------------------------------------
// Kernel B: row L2-normalize replicating numpy pairwise tree (VERBATIM).
// ---------------------------------------------------------------------------
__global__ __launch_bounds__(256) void l2norm_np(float* __restrict__ Q,
                                                 float* __restrict__ K)
{
    const int gid  = blockIdx.x * 256 + threadIdx.x;
    const int w    = gid >> 6;
    const int lane = gid & 63;
    const int wl   = threadIdx.x >> 6;
    float* __restrict__ base = (w < 8192) ? Q : K;
    const long row = (long)(w & 8191);
    float* p = base + row * D_;

    const int bb = lane >> 3, jj = lane & 7;
    const float* seg = p + 96 * bb + jj;
    float r = 0.0f;
#pragma unroll
    for (int i = 0; i < 12; ++i) {
        float xv = seg[8 * i];
        r = __fadd_rn(r, __fmul_rn(xv, xv));
    }

    __shared__ float red[4][64];
    red[wl][lane] = r;
    __syncthreads();

    float Bv[8];
#pragma unroll
    for (int b2 = 0; b2 < 8; ++b2) {
        const float* rr = &red[wl][8 * b2];
        float t1 = __fadd_rn(rr[0], rr[1]);
        float t2 = __fadd_rn(rr[2], rr[3]);
        float t3 = __fadd_rn(rr[4], rr[5]);
        float t4 = __fadd_rn(rr[6], rr[7]);
        Bv[b2] = __fadd_rn(__fadd_rn(t1, t2), __fadd_rn(t3, t4));
    }
    float s01 = __fadd_rn(Bv[0], Bv[1]), s23 = __fadd_rn(Bv[2], Bv[3]);
    float s45 = __fadd_rn(Bv[4], Bv[5]), s67 = __fadd_rn(Bv[6], Bv[7]);
    float tot = __fadd_rn(__fadd_rn(s01, s23), __fadd_rn(s45, s67));

    const float nm = fmaxf(__fsqrt_rn(tot), 1e-12f);

    float* q = p + lane * 12;
#pragma unroll
    for (int i = 0; i < 12; ++i) q[i] = __fdiv_rn(q[i], nm);
}

// ---------------------------------------------------------------------------
// Kernel C: scores, quad-split numpy 16-chain tree. NEW vs r7: kc=32 (halves
// barrier pairs 96->48, doubles per-iter FMA to 128). Bit-exact: lane q's
// accumulator c takes dd = q+4c then q+16+4c per chunk -> same chain
// assignment ((q+4s) mod 16) and same ascending-d order per chain.
// ---------------------------------------------------------------------------
__global__ __launch_bounds__(256) void scores_np(
    const float* __restrict__ Q, const float* __restrict__ K,
    const float* __restrict__ pb, float* __restrict__ S)
{
    const int bz = blockIdx.z;
    const int n0 = blockIdx.x * 32;   // cols
    const int m0 = blockIdx.y * 32;   // rows
    const int t  = threadIdx.x;
    const int q    = t & 3;           // chain-slot lane within quad
    const int quad = t >> 2;          // 0..63
    const int qx   = quad & 7;        // col group (4 cols)
    const int qy   = quad >> 3;       // row group (4 rows)

    __shared__ float Qs[32 * 36];     // [dd][row], stride 36, dd = 0..31
    __shared__ float Ks[32 * 36];     // [dd][col]

    const float* Qb = Q + (((long)bz << 10) + m0) * D_;
    const float* Kb = K + (((long)bz << 10) + n0) * D_;

    // staging: t<128 -> Q tile, t>=128 -> K tile; 32 rows x 4 d-groups;
    // each thread stages d-groups sg (dd=4sg..4sg+3) and sg+4 (dd=16+4sg..).
    const int sr = (t & 127) >> 2;    // row 0..31
    const int sg = t & 3;             // d-group 0..3
    const float* gsrc = (t < 128) ? (Qb + (long)sr * D_ + 4 * sg)
                                  : (Kb + (long)sr * D_ + 4 * sg);
    float* lw = (t < 128) ? Qs : Ks;

    float acc[4][4][4] = {};          // [chain-slot][i][j]

    for (int d0 = 0; d0 < D_; d0 += 32) {
        __syncthreads();
        float4 g0 = *reinterpret_cast<const float4*>(gsrc + d0);
        float4 g1 = *reinterpret_cast<const float4*>(gsrc + d0 + 16);
        lw[(4 * sg + 0) * 36 + sr]      = g0.x;
        lw[(4 * sg + 1) * 36 + sr]      = g0.y;
        lw[(4 * sg + 2) * 36 + sr]      = g0.z;
        lw[(4 * sg + 3) * 36 + sr]      = g0.w;
        lw[(4 * sg + 16) * 36 + sr]     = g1.x;
        lw[(4 * sg + 17) * 36 + sr]     = g1.y;
        lw[(4 * sg + 18) * 36 + sr]     = g1.z;
        lw[(4 * sg + 19) * 36 + sr]     = g1.w;
        __syncthreads();

#pragma unroll
        for (int s = 0; s < 8; ++s) {
            const int dd = q + 4 * (s & 3) + 16 * (s >> 2);   // s<4: q+4s, s>=4: +16
            const int c  = s & 3;                             // accumulator slot
            float4 qv = *reinterpret_cast<const float4*>(&Qs[dd * 36 + 4 * qy]);
            float4 kv = *reinterpret_cast<const float4*>(&Ks[dd * 36 + 4 * qx]);
            float a[4] = {qv.x, qv.y, qv.z, qv.w};
            float b[4] = {kv.x, kv.y, kv.z, kv.w};
#pragma unroll
            for (int i = 0; i < 4; ++i)
#pragma unroll
                for (int j = 0; j < 4; ++j)
                    acc[c][i][j] = fmaf(a[i], b[j], acc[c][i][j]);
        }
    }

    // chains on lane q: slot0=chain q, slot1=q+4, slot2=q+8, slot3=q+12
    // y[q]=slot0+slot2, y[q+4]=slot1+slot3, z[q]=y[q]+y[q+4],
    // dot=(z0+z2)+(z1+z3) via 2 shfl_xor adds.
    float dot[4][4];
#pragma unroll
    for (int i = 0; i < 4; ++i)
#pragma unroll
        for (int j = 0; j < 4; ++j) {
            float ylo = __fadd_rn(acc[0][i][j], acc[2][i][j]);
            float yhi = __fadd_rn(acc[1][i][j], acc[3][i][j]);
            float zz  = __fadd_rn(ylo, yhi);
            float zr  = __shfl_xor(zz, 2, 64);
            float t2  = __fadd_rn(zz, zr);          // lane0: z0+z2, lane1: z1+z3
            float tr  = __shfl_xor(t2, 1, 64);
            dot[i][j] = __fadd_rn(t2, tr);          // lane0: (z0+z2)+(z1+z3)
        }

    if (q == 0) {
        const int c0 = n0 + 4 * qx;
#pragma unroll
        for (int i = 0; i < 4; ++i) {
            const int p = m0 + 4 * qy + i;
            float4 pbv = *reinterpret_cast<const float4*>(pb + (long)p * P_ + c0);
            float v[4] = {__fadd_rn(dot[i][0], pbv.x), __fadd_rn(dot[i][1], pbv.y),
                          __fadd_rn(dot[i][2], pbv.z), __fadd_rn(dot[i][3], pbv.w)};
#pragma unroll
            for (int j = 0; j < 4; ++j)
                if (c0 + j == p) v[j] = NEGV;
            float4 o = {v[0], v[1], v[2], v[3]};
            *reinterpret_cast<float4*>(S + (((long)bz << 10) + p) * P_ + c0) = o;
        }
    }
}

// ---------------------------------------------------------------------------
// Kernel D: top-16 + softmax + V gather (VERBATIM).
// ---------------------------------------------------------------------------
__global__ __launch_bounds__(256) void topk_np(
    const float* __restrict__ S, const float* __restrict__ V,
    float* __restrict__ out)
{
    const int gid  = blockIdx.x * 256 + threadIdx.x;
    const int gw   = gid >> 6;          // row id 0..8191
    const int lane = gid & 63;
    const int b    = gw >> 10;

    const float* srow = S + ((long)gw << 10);
    float s[16];
#pragma unroll
    for (int t = 0; t < 16; ++t) s[t] = __fdiv_rn(srow[lane + 64 * t], 0.1f);

    float topv[16];
    int   topi[16];
#pragma unroll
    for (int r = 0; r < 16; ++r) {
        float bvv = s[0];
        int   bt  = 0;
#pragma unroll
        for (int t = 1; t < 16; ++t)
            if (s[t] > bvv) { bvv = s[t]; bt = t; }
        int bi = lane + 64 * bt;
#pragma unroll
        for (int m = 1; m < 64; m <<= 1) {
            float ov = __shfl_xor(bvv, m, 64);
            int   oi = __shfl_xor(bi, m, 64);
            if (ov > bvv || (ov == bvv && oi < bi)) { bvv = ov; bi = oi; }
        }
        topv[r] = bvv;
        topi[r] = bi;
#pragma unroll
        for (int t = 0; t < 16; ++t)
            if (lane + 64 * t == bi) s[t] = -3.0e38f;
    }

    const float mx = topv[0];
    float e[16];
#pragma unroll
    for (int r = 0; r < 16; ++r) e[r] = expf(topv[r] - mx);
    float r8[8];
#pragma unroll
    for (int j = 0; j < 8; ++j) r8[j] = __fadd_rn(e[j], e[j + 8]);
    float t1 = __fadd_rn(r8[0], r8[1]);
    float t2 = __fadd_rn(r8[2], r8[3]);
    float t3 = __fadd_rn(r8[4], r8[5]);
    float t4 = __fadd_rn(r8[6], r8[7]);
    float sum = __fadd_rn(__fadd_rn(t1, t2), __fadd_rn(t3, t4));
    float wgt[16];
#pragma unroll
    for (int r = 0; r < 16; ++r) wgt[r] = __fdiv_rn(e[r], sum);

    float4 a0 = {0, 0, 0, 0}, a1 = {0, 0, 0, 0}, a2 = {0, 0, 0, 0};
    const float* vb = V + ((long)b << 10) * D_;
#pragma unroll
    for (int r = 0; r < 16; ++r) {
        const float* vr = vb + (long)topi[r] * D_ + lane * 12;
        const float wr = wgt[r];
        float4 x0 = *reinterpret_cast<const float4*>(vr);
        float4 x1 = *reinterpret_cast<const float4*>(vr + 4);
        float4 x2 = *reinterpret_cast<const float4*>(vr + 8);
        a0.x = fmaf(wr, x0.x, a0.x); a0.y = fmaf(wr, x0.y, a0.y);
        a0.z = fmaf(wr, x0.z, a0.z); a0.w = fmaf(wr, x0.w, a0.w);
        a1.x = fmaf(wr, x1.x, a1.x); a1.y = fmaf(wr, x1.y, a1.y);
        a1.z = fmaf(wr, x1.z, a1.z); a1.w = fmaf(wr, x1.w, a1.w);
        a2.x = fmaf(wr, x2.x, a2.x); a2.y = fmaf(wr, x2.y, a2.y);
        a2.z = fmaf(wr, x2.z, a2.z); a2.w = fmaf(wr, x2.w, a2.w);
    }
    float* orow = out + (long)gw * D_ + lane * 12;
    *reinterpret_cast<float4*>(orow)     = a0;
    *reinterpret_cast<float4*>(orow + 4) = a1;
    *reinterpret_cast<float4*>(orow + 8) = a2;
}

// ---------------------------------------------------------------------------
extern "C" void kernel_launch(void* const* d_in, const int* in_sizes, int n_in,
                              void* d_out, int out_size, void* d_ws, size_t ws_size,
                              hipStream_t stream)
{
    const float* x  = (const float*)d_in[0];
    const float* Wq = (const float*)d_in[1];
    const float* bq = (const float*)d_in[2];
    const float* Wk = (const float*)d_in[3];
    const float* bk = (const float*)d_in[4];
    const float* Wv = (const float*)d_in[5];
    const float* bv = (const float*)d_in[6];
    const float* pb = (const float*)d_in[7];
    float* out = (float*)d_out;

    // Workspace (fp32): Q | K | V (8192x768 each) | S (8192x1024)
    float* ws = (float*)d_ws;
    float* Q = ws;
    float* K = Q + (size_t)B_ * P_ * D_;
    float* V = K + (size_t)B_ * P_ * D_;
    float* S = V + (size_t)B_ * P_ * D_;

    hipLaunchKernelGGL(gemm_qkv_np, dim3(6, 64, 3), dim3(256), 0, stream,
                       x, Wq, bq, Wk, bk, Wv, bv, Q, K, V);
    hipLaunchKernelGGL(l2norm_np, dim3(4096), dim3(256), 0, stream, Q, K);
    hipLaunchKernelGGL(scores_np, dim3(32, 32, 8), dim3(256), 0, stream,
                       Q, K, pb, S);
    hipLaunchKernelGGL(topk_np, dim3(2048), dim3(256), 0, stream,
                       S, V, out);
}